// Round 5
// baseline (90.299 us; speedup 1.0000x reference)
//
#include <hip/hip_runtime.h>
#include <math.h>

// ContrastiveLoss — x (8,128,16,8,8) fp32.
// feats[n,f] = x[b*131072 + f*1024 + r], n=(b<<10)|r, N=8192, F=128.
// loss = 10 + ln( sum_{i!=j} exp(10*dot(x̂_i,x̂_j) - 10) )   (unit rows => s<=10)
//
// Round 5: gram with FULL prefetch — all 32 fragments (512B/lane) issued
// before any MFMA, so the kernel is L2-BW-bound (Little's law: need ~200B/lane
// in flight to cover ~225cyc L2 latency; we have 512B). 2D grid + early exit
// (no scalar decode loop). fp32 partials/reduction. No LDS, no barriers, no
// atomics in gram.
//
// Swizzled X̂ layout (verified rounds 2-4, absmax 0): row-group rg=n>>4 (16
// rows, 2048 shorts). 16B chunk (t*64 + q*16 + (n&15)) holds k = t*32+q*8+j —
// exactly the mfma_f32_16x16x32_bf16 A/B fragment order for lane q*16+(n&15).
//
// ws: partials float[16384] @0 (64KB); Xs bf16[8192*128] @131072 (2MB).

typedef __attribute__((ext_vector_type(8))) short short8;
typedef __bf16 bf16_t;
typedef __attribute__((ext_vector_type(8))) bf16_t bf16x8;
typedef __attribute__((ext_vector_type(4))) float f32x4;

#if __has_builtin(__builtin_amdgcn_exp2f)
#define EXP2F(x) __builtin_amdgcn_exp2f(x)
#else
#define EXP2F(x) exp2f(x)
#endif

// Adapter: compiles whether the mfma builtin takes short8 or bf16x8 operands.
struct Frag {
    short8 s;
    __device__ operator short8() const { return s; }
    __device__ operator bf16x8() const { return __builtin_bit_cast(bf16x8, s); }
};

__device__ inline short f2bf(float f) {  // RNE fp32->bf16 (inputs finite)
    unsigned u = __float_as_uint(f);
    u += 0x7fff + ((u >> 16) & 1);
    return (short)(u >> 16);
}

// ---------------------------------------------------------------------------
// Kernel 1: normalize + swizzle, full GPU. Block = 32 rows (same b).
// Phase 1: coalesced global read (each element once) -> LDS (pad 33).
// Phase 2: consecutive tid -> consecutive 16B output chunks (coalesced).
// All LDS phases <=2-way bank aliasing (free on CDNA4).
// ---------------------------------------------------------------------------
__global__ __launch_bounds__(256)
void normalize_kernel(const float* __restrict__ x, short* __restrict__ Xs) {
    __shared__ float ldsf[128][33];
    __shared__ float ssred[8][32];
    __shared__ float invs[32];
    const int tid = threadIdx.x;
    const int b  = blockIdx.x >> 5;
    const int r0 = (blockIdx.x & 31) * 32;
    const int rl = tid & 31, fp = tid >> 5;   // row-in-block, feature-part
    const float* px = x + b * 131072 + r0 + rl;
    float ss = 0.f;
#pragma unroll
    for (int j = 0; j < 16; ++j) {
        int f = fp * 16 + j;
        float v = px[f * 1024];
        ldsf[f][rl] = v;
        ss = fmaf(v, v, ss);
    }
    ssred[fp][rl] = ss;
    __syncthreads();
    if (tid < 32) {
        float s = 0.f;
#pragma unroll
        for (int k = 0; k < 8; ++k) s += ssred[k][tid];
        invs[tid] = 1.0f / fmaxf(sqrtf(s), 1e-12f);
    }
    __syncthreads();
#pragma unroll
    for (int p = 0; p < 2; ++p) {
        int c = p * 256 + tid;                       // chunk id, output-ordered
        int grp = c >> 8, tt = (c >> 6) & 3, q = (c >> 4) & 3, r16 = c & 15;
        int lr = grp * 16 + r16;                     // local row 0..31
        float inv = invs[lr];
        union { short s[8]; int4 v; } u;
#pragma unroll
        for (int j = 0; j < 8; ++j)
            u.s[j] = f2bf(ldsf[tt * 32 + q * 8 + j][lr] * inv);
        int rg = (((b << 10) + r0) >> 4) + grp;      // global row-group
        *(int4*)(Xs + ((rg * 256 + tt * 64 + q * 16 + r16) << 3)) = u.v;
    }
}

// ---------------------------------------------------------------------------
// Kernel 2: 128x128 Gram tile, ALL 32 fragments prefetched before MFMA.
// 2D grid (64,64); J<I blocks zero their 4 per-wave slots and exit.
// No LDS, no barriers. Per-wave fp32 partial to its own slot.
// ---------------------------------------------------------------------------
__global__ __launch_bounds__(256)
void gram_lse_kernel(const short* __restrict__ Xs, float* __restrict__ partials) {
    const int I = blockIdx.x, J = blockIdx.y;
    const int bid = (J << 6) + I;
    const int tid = threadIdx.x;
    const int lane = tid & 63, w = tid >> 6;
    if (J < I) { if (lane == 0) partials[bid * 4 + w] = 0.f; return; }

    const int gi0 = (w & 1) * 4;         // A row-group base within tile
    const int gj0 = (w >> 1) * 4;        // B row-group base within tile
    const short8* A = (const short8*)(Xs + I * 16384) + gi0 * 256 + lane;
    const short8* B = (const short8*)(Xs + J * 16384) + gj0 * 256 + lane;

    // Full prefetch: 32 outstanding dwordx4 loads per lane (512B in flight).
    // Issue order t-major so the first MFMAs can start at vmcnt(24).
    short8 a[4][4], b[4][4];             // [row-group][k-step]
#pragma unroll
    for (int t = 0; t < 4; ++t)
#pragma unroll
        for (int g = 0; g < 4; ++g) {
            a[g][t] = A[g * 256 + t * 64];
            b[g][t] = B[g * 256 + t * 64];
        }

    f32x4 acc[4][4];
#pragma unroll
    for (int i = 0; i < 4; ++i)
#pragma unroll
        for (int j = 0; j < 4; ++j) acc[i][j] = (f32x4){0.f, 0.f, 0.f, 0.f};

#pragma unroll
    for (int t = 0; t < 4; ++t)
#pragma unroll
        for (int i = 0; i < 4; ++i)
#pragma unroll
            for (int j = 0; j < 4; ++j)
                acc[i][j] = __builtin_amdgcn_mfma_f32_16x16x32_bf16(
                    Frag{a[i][t]}, Frag{b[j][t]}, acc[i][j], 0, 0, 0);

    // Epilogue: C/D layout col=lane&15, row=(lane>>4)*4+reg (verified m89/m91).
    // exp(10d-10) = exp2(C*d - C), C = 10*log2(e)
    const float C = 14.426950408889634f;
    const bool diagT = (I == J);
    const int quad = lane >> 4, colL = lane & 15;
    float lsum = 0.f;
#pragma unroll
    for (int i = 0; i < 4; ++i) {
        const int rbase = (gi0 + i) * 16 + quad * 4;   // row within tile
#pragma unroll
        for (int j = 0; j < 4; ++j) {
            const int cbase = (gj0 + j) * 16 + colL;   // col within tile
#pragma unroll
            for (int g = 0; g < 4; ++g) {
                if (diagT && (rbase + g == cbase)) continue;
                lsum += EXP2F(fmaf(C, acc[i][j][g], -C));
            }
        }
    }
    if (!diagT) lsum *= 2.0f;            // symmetry weight
#pragma unroll
    for (int o = 32; o > 0; o >>= 1) lsum += __shfl_down(lsum, o, 64);
    if (lane == 0) partials[bid * 4 + w] = lsum;   // per-wave slot, no barrier
}

// ---------------------------------------------------------------------------
// Kernel 3: out = 10 + ln(sum of 16384 fp32 partials), f64 accumulation.
// ---------------------------------------------------------------------------
__global__ __launch_bounds__(256)
void final_kernel(const float* __restrict__ partials, float* __restrict__ out) {
    double s = 0.0;
    for (int i = threadIdx.x; i < 16384; i += 256) s += (double)partials[i];
#pragma unroll
    for (int o = 32; o > 0; o >>= 1) s += __shfl_down(s, o, 64);
    __shared__ double red[4];
    if ((threadIdx.x & 63) == 0) red[threadIdx.x >> 6] = s;
    __syncthreads();
    if (threadIdx.x == 0)
        out[0] = (float)(10.0 + log(red[0] + red[1] + red[2] + red[3]));
}

extern "C" void kernel_launch(void* const* d_in, const int* in_sizes, int n_in,
                              void* d_out, int out_size, void* d_ws, size_t ws_size,
                              hipStream_t stream) {
    const float* x = (const float*)d_in[0];
    float* out = (float*)d_out;
    float* partials = (float*)d_ws;                   // 16384 floats (64KB)
    short* Xs = (short*)((char*)d_ws + 131072);       // 2MB swizzled bf16 X̂

    normalize_kernel<<<256, 256, 0, stream>>>(x, Xs);
    gram_lse_kernel<<<dim3(64, 64), 256, 0, stream>>>(Xs, partials);
    final_kernel<<<1, 256, 0, stream>>>(partials, out);
}

// Round 7
// 81.587 us; speedup vs baseline: 1.1068x; 1.1068x over previous
//
#include <hip/hip_runtime.h>
#include <hip/hip_fp8.h>
#include <math.h>

// ContrastiveLoss — x (8,128,16,8,8) fp32 (4 MB).
// feats[n,f] = x[b*131072 + f*1024 + r], n=(b<<10)|r, N=8192, F=128.
// loss = 10 + ln( sum_{i!=j} exp(10*dot(x̂_i,x̂_j) - 10) )   (unit rows => s<=10)
//
// Round 7: fp8-e4m3 MFMA gram (16x16x32_fp8_fp8), 64x64 tiles, 32x32 per
// wave, ~70 VGPR -> 6 waves/SIMD (24 waves/CU). Persistent 1536-block grid
// (6 blocks/CU), each block loops ~5.4 tiles with NO barriers in the loop —
// loads of tile t+1 overlap the exp epilogue of tile t. fp8 halves traffic
// (~132 MB L2). Accuracy: fp8 RNE dot noise ~0.01 on loss vs 0.37 threshold.
//
// fp8 swizzled layout: row-group rg=n>>4 (16 rows, 2KB). 16B chunk
// (t8*64 + q*16 + r) holds, for lane q*16+r: bytes[half*8+j] = x̂[row r of rg]
// [k = t8*64 + half*32 + q*8 + j]. One dwordx4 = the lane's A/B fragments for
// k-steps 2*t8 (low 8B) and 2*t8+1 (high 8B) of mfma_f32_16x16x32_fp8_fp8
// (A[m=lane&15][k=quad*8+j] — same index pattern as the verified bf16 family;
// C/D layout dtype-independent: col=lane&15, row=(lane>>4)*4+reg).
//
// ws: partials float[1536] @0; Xs fp8[8192*128] @131072 (1MB).

#define NTILE 8256   // 128*129/2 upper-triangle 64x64 tiles
#define NPBLK 1536   // persistent blocks = 6 per CU

typedef __attribute__((ext_vector_type(4))) float f32x4;

__device__ inline unsigned char f2fp8(float f) {   // OCP e4m3fn, RNE
    __hip_fp8_e4m3 h(f);
    return h.__x;
}

// ---------------------------------------------------------------------------
// Kernel 1: normalize + fp8 swizzle. Block = 32 rows (2 row-groups).
// Phase 1: coalesced read of x (each element once) into LDS (pad 33).
// Phase 2: one 16B output chunk per thread, consecutive tid -> consecutive
// chunks; LDS reads <=2-way bank aliased (free).
// ---------------------------------------------------------------------------
__global__ __launch_bounds__(256)
void normalize_kernel(const float* __restrict__ x, unsigned char* __restrict__ Xs) {
    __shared__ float ldsf[128][33];
    __shared__ float ssred[8][32];
    __shared__ float invs[32];
    const int tid = threadIdx.x;
    const int b  = blockIdx.x >> 5;
    const int r0 = (blockIdx.x & 31) * 32;
    const int rl = tid & 31, fp = tid >> 5;       // row-in-block, f-slot
    const float* px = x + b * 131072 + r0 + rl;
    float ss = 0.f;
#pragma unroll
    for (int j = 0; j < 16; ++j) {
        int f = fp * 16 + j;
        float v = px[f * 1024];
        ldsf[f][rl] = v;
        ss = fmaf(v, v, ss);
    }
    ssred[fp][rl] = ss;
    __syncthreads();
    if (tid < 32) {
        float s = 0.f;
#pragma unroll
        for (int k = 0; k < 8; ++k) s += ssred[k][tid];
        invs[tid] = 1.0f / fmaxf(sqrtf(s), 1e-12f);
    }
    __syncthreads();
    {   // one 16B chunk per thread
        const int c   = tid;
        const int rgl = c >> 7;                   // local row-group 0..1
        const int cc  = c & 127;                  // chunk within row-group
        const int t8  = (cc >> 6) & 1, q = (cc >> 4) & 3, r = cc & 15;
        const int row = rgl * 16 + r;             // local row 0..31
        const float inv = invs[row];
        union { unsigned char bytes[16]; int4 v; } u;
#pragma unroll
        for (int half = 0; half < 2; ++half)
#pragma unroll
            for (int j = 0; j < 8; ++j) {
                int k = t8 * 64 + half * 32 + q * 8 + j;
                u.bytes[half * 8 + j] = f2fp8(ldsf[k][row] * inv);
            }
        const int rgg = blockIdx.x * 2 + rgl;     // global row-group
        ((int4*)Xs)[rgg * 128 + cc] = u.v;
    }
}

// ---------------------------------------------------------------------------
// Kernel 2: persistent gram. Block k handles tiles k, k+1536, ... (~5.4 each).
// 64x64 tile = 4 row-groups; wave w: A rgs (w&1)*2..+1, B rgs (w>>1)*2..+1.
// Per tile: 8 dwordx4 loads, 16 fp8 MFMAs, 16-elem exp epilogue. No barriers
// inside the loop; per-thread wsum across tiles; one block reduce at the end.
// ---------------------------------------------------------------------------
__global__ __launch_bounds__(256, 6)
void gram_lse_kernel(const int4* __restrict__ Xs, float* __restrict__ partials) {
    const int bk = blockIdx.x;
    const int tid = threadIdx.x;
    const int lane = tid & 63, w = tid >> 6;
    const int ga = (w & 1) * 2;                  // A rg offset within tile
    const int gb = (w >> 1) * 2;                 // B rg offset within tile
    const int quad = lane >> 4, colL = lane & 15;
    const float C = 14.426950408889634f;         // 10*log2(e)
    float wsum = 0.f;

    for (int tile = bk; tile < NTILE; tile += NPBLK) {
        int L = tile, I = 0;                     // triangle decode (<=128 iters)
        while (L >= 128 - I) { L -= 128 - I; ++I; }
        const int J = I + L;

        const int argb = I * 4 + ga;             // global rg of A rows
        const int brgb = J * 4 + gb;
        int4 av[2][2], bv[2][2];                 // [g][t8]
#pragma unroll
        for (int g = 0; g < 2; ++g)
#pragma unroll
            for (int t8 = 0; t8 < 2; ++t8) {
                av[g][t8] = Xs[(argb + g) * 128 + t8 * 64 + lane];
                bv[g][t8] = Xs[(brgb + g) * 128 + t8 * 64 + lane];
            }

        f32x4 acc[2][2];
#pragma unroll
        for (int i = 0; i < 2; ++i)
#pragma unroll
            for (int j = 0; j < 2; ++j) acc[i][j] = (f32x4){0.f, 0.f, 0.f, 0.f};

#pragma unroll
        for (int t = 0; t < 4; ++t) {            // K-steps of 32
            long aL[2], bL[2];
#pragma unroll
            for (int g = 0; g < 2; ++g) {
                aL[g] = ((const long*)&av[g][t >> 1])[t & 1];
                bL[g] = ((const long*)&bv[g][t >> 1])[t & 1];
            }
#pragma unroll
            for (int i = 0; i < 2; ++i)
#pragma unroll
                for (int j = 0; j < 2; ++j)
                    acc[i][j] = __builtin_amdgcn_mfma_f32_16x16x32_fp8_fp8(
                        aL[i], bL[j], acc[i][j], 0, 0, 0);
        }

        // C/D: col=lane&15, row=(lane>>4)*4+reg (dtype-independent, verified)
        const bool diagT = (I == J);
        float lsum = 0.f;
#pragma unroll
        for (int i = 0; i < 2; ++i) {
            const int rbase = (ga + i) * 16 + quad * 4;   // row within tile
#pragma unroll
            for (int j = 0; j < 2; ++j) {
                const int cbase = (gb + j) * 16 + colL;   // col within tile
#pragma unroll
                for (int g = 0; g < 4; ++g) {
                    if (diagT && (rbase + g == cbase)) continue;
                    lsum += exp2f(fmaf(C, acc[i][j][g], -C));
                }
            }
        }
        wsum += diagT ? lsum : 2.0f * lsum;      // symmetry weight
    }

#pragma unroll
    for (int o = 32; o > 0; o >>= 1) wsum += __shfl_down(wsum, o, 64);
    __shared__ float red[4];
    if (lane == 0) red[w] = wsum;
    __syncthreads();
    if (tid == 0) partials[bk] = red[0] + red[1] + red[2] + red[3];
}

// ---------------------------------------------------------------------------
// Kernel 3: out = 10 + ln(sum of 1536 partials), f64 accumulation.
// ---------------------------------------------------------------------------
__global__ __launch_bounds__(256)
void final_kernel(const float* __restrict__ partials, float* __restrict__ out) {
    double s = 0.0;
    for (int i = threadIdx.x; i < NPBLK; i += 256) s += (double)partials[i];
#pragma unroll
    for (int o = 32; o > 0; o >>= 1) s += __shfl_down(s, o, 64);
    __shared__ double red[4];
    if ((threadIdx.x & 63) == 0) red[threadIdx.x >> 6] = s;
    __syncthreads();
    if (threadIdx.x == 0)
        out[0] = (float)(10.0 + log(red[0] + red[1] + red[2] + red[3]));
}

extern "C" void kernel_launch(void* const* d_in, const int* in_sizes, int n_in,
                              void* d_out, int out_size, void* d_ws, size_t ws_size,
                              hipStream_t stream) {
    const float* x = (const float*)d_in[0];
    float* out = (float*)d_out;
    float* partials = (float*)d_ws;                         // 1536 floats
    unsigned char* Xs = (unsigned char*)d_ws + 131072;      // 1MB fp8 X̂

    normalize_kernel<<<256, 256, 0, stream>>>(x, Xs);
    gram_lse_kernel<<<NPBLK, 256, 0, stream>>>((const int4*)Xs, partials);
    final_kernel<<<1, 256, 0, stream>>>(partials, out);
}